// Round 6
// baseline (257.183 us; speedup 1.0000x reference)
//
#include <hip/hip_runtime.h>
#include <hip/hip_bf16.h>

// ---------------------------------------------------------------------------
// ResidualAttentionBlock: LN1 -> QKV -> MHA -> out-proj(+x) -> LN2 -> FFN(+x)
// B=4, S=1024, d=1024, H=16, dh=64.
//   - GEMMs: MFMA bf16, 128x128 tile, BK=32, global_load_lds, 2-phase LDS dbuf.
//   - QK GEMM (N=2048): split-bf16 (hi+lo) x3 MFMA -> Q(x0.125),K split bf16.
//   - V GEMM (N=1024): plain bf16 -> V transposed [b,h,dim,key].
//   - Attention: MFMA flash, swapped QK^T, XCD-aware grid, P redistributed
//     via 16 register shuffles (no P LDS) -> 48KB LDS, 3 blocks/CU.
// ---------------------------------------------------------------------------

typedef short bf16x8 __attribute__((ext_vector_type(8)));
typedef float f32x4 __attribute__((ext_vector_type(4)));
typedef unsigned int u32x4 __attribute__((ext_vector_type(4)));

__device__ __forceinline__ unsigned short f2bf(float f) {
  unsigned int u = __float_as_uint(f);
  unsigned int r = (u + 0x7fffu + ((u >> 16) & 1u)) >> 16;
  return (unsigned short)r;
}
__device__ __forceinline__ float bf2f(unsigned short h) {
  return __uint_as_float(((unsigned int)h) << 16);
}

__device__ __forceinline__ void gld16(const void* g, void* l) {
  __builtin_amdgcn_global_load_lds(
      (const __attribute__((address_space(1))) unsigned int*)g,
      (__attribute__((address_space(3))) unsigned int*)l, 16, 0, 0);
}

// ---------------- weight prep ----------------

__global__ void cast_split_kernel(const float* __restrict__ in,
                                  unsigned short* __restrict__ hi,
                                  unsigned short* __restrict__ lo, int n) {
  int i = blockIdx.x * blockDim.x + threadIdx.x;
  int stride = gridDim.x * blockDim.x;
  for (; i < n; i += stride) {
    float v = in[i];
    unsigned short h = f2bf(v);
    hi[i] = h;
    lo[i] = f2bf(v - bf2f(h));
  }
}

// three transposes in one launch (z selects matrix)
__global__ void transpose3_kernel(const float* __restrict__ op,
                                  const float* __restrict__ wu,
                                  const float* __restrict__ wd,
                                  unsigned short* __restrict__ oT,
                                  unsigned short* __restrict__ uT,
                                  unsigned short* __restrict__ dT) {
  const float* in;
  unsigned short* out;
  int R, C;
  if (blockIdx.z == 0) { in = op; out = oT; R = 1024; C = 1024; }
  else if (blockIdx.z == 1) { in = wu; out = uT; R = 1024; C = 2048; }
  else { in = wd; out = dT; R = 2048; C = 1024; }
  int bc = blockIdx.x << 5;
  int br = blockIdx.y << 5;
  if (bc >= C || br >= R) return;
  __shared__ float t[32][33];
  int tx = threadIdx.x, ty = threadIdx.y;
#pragma unroll
  for (int i = ty; i < 32; i += 8)
    t[i][tx] = in[(size_t)(br + i) * C + bc + tx];
  __syncthreads();
#pragma unroll
  for (int i = ty; i < 32; i += 8)
    out[(size_t)(bc + i) * R + br + tx] = f2bf(t[tx][i]);
}

// ---------------- layernorm (d=1024 fixed) ----------------

template <bool SPLIT>
__global__ __launch_bounds__(256) void ln_kernel(
    const float* __restrict__ x, const float* __restrict__ gamma,
    const float* __restrict__ beta, unsigned short* __restrict__ hi,
    unsigned short* __restrict__ lo) {
  int row = blockIdx.x, tid = threadIdx.x;
  float4 v = ((const float4*)x)[(size_t)row * 256 + tid];
  float s = v.x + v.y + v.z + v.w;
  float ss = v.x * v.x + v.y * v.y + v.z * v.z + v.w * v.w;
#pragma unroll
  for (int off = 32; off; off >>= 1) {
    s += __shfl_xor(s, off);
    ss += __shfl_xor(ss, off);
  }
  __shared__ float red[8];
  int wid = tid >> 6, lane = tid & 63;
  if (lane == 0) { red[wid] = s; red[4 + wid] = ss; }
  __syncthreads();
  s = red[0] + red[1] + red[2] + red[3];
  ss = red[4] + red[5] + red[6] + red[7];
  float mean = s * (1.f / 1024.f);
  float var = ss * (1.f / 1024.f) - mean * mean;
  float inv = rsqrtf(var + 1e-5f);
  float4 g = ((const float4*)gamma)[tid];
  float4 bt = ((const float4*)beta)[tid];
  float y[4];
  y[0] = (v.x - mean) * inv * g.x + bt.x;
  y[1] = (v.y - mean) * inv * g.y + bt.y;
  y[2] = (v.z - mean) * inv * g.z + bt.z;
  y[3] = (v.w - mean) * inv * g.w + bt.w;
  size_t o = (size_t)row * 1024 + tid * 4;
#pragma unroll
  for (int j = 0; j < 4; ++j) {
    unsigned short hb = f2bf(y[j]);
    hi[o + j] = hb;
    if (SPLIT) lo[o + j] = f2bf(y[j] - bf2f(hb));
  }
}

// ---------------- GEMM: C[M,N] = A[M,K] * W[N,K]^T ----------------
// bf16 MFMA 16x16x32, tile 128x128, BK=32, 4 waves, 2-phase LDS dbuf.
// OUTMODE: 0 normal, 1 QK-split epilogue (N=2048), 2 V-transpose epilogue.

template <bool SPLIT, bool BIAS, bool RESID, bool RELU, bool OUTBF16,
          int OUTMODE>
__global__ __launch_bounds__(256) void gemm_kernel(
    const short* __restrict__ Ah, const short* __restrict__ Al,
    const short* __restrict__ Bh, const short* __restrict__ Bl,
    const float* __restrict__ bias, const float* __restrict__ resid,
    void* __restrict__ outp, int M, int N, int K,
    unsigned short* __restrict__ qh, unsigned short* __restrict__ ql,
    unsigned short* __restrict__ kh, unsigned short* __restrict__ kl,
    unsigned short* __restrict__ vtp) {
  __shared__ short As[2][128 * 32];
  __shared__ short Bs[2][128 * 32];
  __shared__ short As2[SPLIT ? 2 : 1][SPLIT ? 128 * 32 : 8];
  __shared__ short Bs2[SPLIT ? 2 : 1][SPLIT ? 128 * 32 : 8];

  const int tid = threadIdx.x;
  const int lane = tid & 63;
  const int wid = tid >> 6;
  const int wr = (wid >> 1) << 6;
  const int wc = (wid & 1) << 6;
  const int l15 = lane & 15, lh = lane >> 4;
  const int rowBase = blockIdx.y << 7;
  const int colBase = blockIdx.x << 7;

  const int sr = tid >> 2;
  const int sc = (tid & 3) << 3;
  const int soff = sr * 32 + sc;
  const short* Ag = Ah + (size_t)(rowBase + sr) * K + sc;
  const short* Bg = Bh + (size_t)(colBase + sr) * K + sc;
  const short* Ag2 = SPLIT ? Al + (size_t)(rowBase + sr) * K + sc : nullptr;
  const short* Bg2 = SPLIT ? Bl + (size_t)(colBase + sr) * K + sc : nullptr;

  f32x4 acc[4][4];
#pragma unroll
  for (int m = 0; m < 4; ++m)
#pragma unroll
    for (int n = 0; n < 4; ++n) acc[m][n] = (f32x4){0.f, 0.f, 0.f, 0.f};

  const int kT = K >> 5;
  {
    gld16(Ag, &As[0][soff]);
    gld16(Ag + (size_t)64 * K, &As[0][soff + 64 * 32]);
    gld16(Bg, &Bs[0][soff]);
    gld16(Bg + (size_t)64 * K, &Bs[0][soff + 64 * 32]);
    if constexpr (SPLIT) {
      gld16(Ag2, &As2[0][soff]);
      gld16(Ag2 + (size_t)64 * K, &As2[0][soff + 64 * 32]);
      gld16(Bg2, &Bs2[0][soff]);
      gld16(Bg2 + (size_t)64 * K, &Bs2[0][soff + 64 * 32]);
    }
  }

  for (int kt = 0; kt < kT; ++kt) {
    __syncthreads();
    const int cb = kt & 1;
    if (kt + 1 < kT) {
      const int nb = cb ^ 1;
      const int k0 = (kt + 1) << 5;
      gld16(Ag + k0, &As[nb][soff]);
      gld16(Ag + k0 + (size_t)64 * K, &As[nb][soff + 64 * 32]);
      gld16(Bg + k0, &Bs[nb][soff]);
      gld16(Bg + k0 + (size_t)64 * K, &Bs[nb][soff + 64 * 32]);
      if constexpr (SPLIT) {
        gld16(Ag2 + k0, &As2[nb][soff]);
        gld16(Ag2 + k0 + (size_t)64 * K, &As2[nb][soff + 64 * 32]);
        gld16(Bg2 + k0, &Bs2[nb][soff]);
        gld16(Bg2 + k0 + (size_t)64 * K, &Bs2[nb][soff + 64 * 32]);
      }
    }

    const short* Asb = As[cb];
    const short* Bsb = Bs[cb];
    bf16x8 af[4], bfr[4];
#pragma unroll
    for (int m = 0; m < 4; ++m)
      af[m] = *(const bf16x8*)&Asb[(wr + m * 16 + l15) * 32 + lh * 8];
#pragma unroll
    for (int n = 0; n < 4; ++n)
      bfr[n] = *(const bf16x8*)&Bsb[(wc + n * 16 + l15) * 32 + lh * 8];
    if constexpr (SPLIT) {
      const short* Asb2 = As2[cb];
      const short* Bsb2 = Bs2[cb];
      bf16x8 af2[4], bfr2[4];
#pragma unroll
      for (int m = 0; m < 4; ++m)
        af2[m] = *(const bf16x8*)&Asb2[(wr + m * 16 + l15) * 32 + lh * 8];
#pragma unroll
      for (int n = 0; n < 4; ++n)
        bfr2[n] = *(const bf16x8*)&Bsb2[(wc + n * 16 + l15) * 32 + lh * 8];
#pragma unroll
      for (int m = 0; m < 4; ++m)
#pragma unroll
        for (int n = 0; n < 4; ++n) {
          acc[m][n] = __builtin_amdgcn_mfma_f32_16x16x32_bf16(af[m], bfr[n], acc[m][n], 0, 0, 0);
          acc[m][n] = __builtin_amdgcn_mfma_f32_16x16x32_bf16(af[m], bfr2[n], acc[m][n], 0, 0, 0);
          acc[m][n] = __builtin_amdgcn_mfma_f32_16x16x32_bf16(af2[m], bfr[n], acc[m][n], 0, 0, 0);
        }
    } else {
#pragma unroll
      for (int m = 0; m < 4; ++m)
#pragma unroll
        for (int n = 0; n < 4; ++n)
          acc[m][n] = __builtin_amdgcn_mfma_f32_16x16x32_bf16(af[m], bfr[n], acc[m][n], 0, 0, 0);
    }
  }

  const int prow = rowBase + wr + lh * 4;
  const int pcol = colBase + wc + l15;
#pragma unroll
  for (int m = 0; m < 4; ++m) {
#pragma unroll
    for (int n = 0; n < 4; ++n) {
      const int c = pcol + n * 16;
      float badd = 0.f;
      if constexpr (BIAS) badd = bias[c];
#pragma unroll
      for (int i = 0; i < 4; ++i) {
        const int r = prow + m * 16 + i;
        float v = acc[m][n][i] + badd;
        if constexpr (OUTMODE == 1) {
          const int part = c >> 10;
          const int cc = c & 1023;
          const int head = cc >> 6, dim = cc & 63;
          const int b = r >> 10, s = r & 1023;
          size_t idx = (((size_t)(b * 16 + head)) * 1024 + s) * 64 + dim;
          if (part == 0) {
            float y = v * 0.125f;
            unsigned short hb = f2bf(y);
            qh[idx] = hb;
            ql[idx] = f2bf(y - bf2f(hb));
          } else {
            unsigned short hb = f2bf(v);
            kh[idx] = hb;
            kl[idx] = f2bf(v - bf2f(hb));
          }
        } else if constexpr (OUTMODE == 2) {
          const int head = c >> 6, dim = c & 63;
          const int b = r >> 10, s = r & 1023;
          vtp[(((size_t)(b * 16 + head)) * 64 + dim) * 1024 + s] = f2bf(v);
        } else {
          if constexpr (RESID) v += resid[(size_t)r * N + c];
          if constexpr (RELU) v = fmaxf(v, 0.f);
          if constexpr (OUTBF16)
            ((unsigned short*)outp)[(size_t)r * N + c] = f2bf(v);
          else
            ((float*)outp)[(size_t)r * N + c] = v;
        }
      }
    }
  }
}

// ---------------- attention: MFMA flash, swapped QK^T, reg-shuffled P ------
// 1D grid of 512 blocks, 512 threads (8 waves x 16 q-rows).
// XCD decode: blk&7 = xcd slot, each xcd owns 8 heads -> K/V L2-resident.
// Swapped scores: accs[n][i] = score[key=16n+4g+i][q=l15] (g=lh).
// P for PV's A-frag (lane needs P[q=l15][key=8g+j]) is rebuilt in-register:
//   pack accs into dwords dw[n][0..1], then 16 __shfl from lanes
//   s0 = l15+32*(g&1), s1 = s0+16; select register set by g>>1.
// No P LDS -> 48KB LDS, 3 blocks/CU (launch_bounds 512,6).

__global__ __launch_bounds__(512, 6) void attn_mfma_kernel(
    const short* __restrict__ qhi, const short* __restrict__ qlo,
    const short* __restrict__ khi, const short* __restrict__ klo,
    const short* __restrict__ vt, unsigned short* __restrict__ o,
    int S, int H) {
  __shared__ short Kh[2][64 * 64];
  __shared__ short Kl[2][64 * 64];
  __shared__ short Vs[2][64 * 64];

  const int tid = threadIdx.x, lane = tid & 63, wid = tid >> 6;
  const int l15 = lane & 15, lh = lane >> 4;
  const int blk = blockIdx.x;
  const int j = blk >> 3;
  const int bh = ((blk & 7) << 3) + (j & 7);
  const int q0 = (j >> 3) << 7;
  const size_t hb = (size_t)bh * S * 64;

  const size_t qrow = hb + (size_t)(q0 + wid * 16 + l15) * 64;
  bf16x8 aqh[2], aql[2];
  aqh[0] = *(const bf16x8*)(qhi + qrow + lh * 8);
  aqh[1] = *(const bf16x8*)(qhi + qrow + 32 + lh * 8);
  aql[0] = *(const bf16x8*)(qlo + qrow + lh * 8);
  aql[1] = *(const bf16x8*)(qlo + qrow + 32 + lh * 8);

  // softmax state: per-lane, query = l15; l_run partial over this lh slice
  float m_run = -INFINITY, l_run = 0.f;
  // PV accumulator: query = lh*4+i, dim = n*16+l15
  f32x4 acc_o[4];
#pragma unroll
  for (int n = 0; n < 4; ++n) acc_o[n] = (f32x4){0.f, 0.f, 0.f, 0.f};

  const int r0 = tid >> 3, c0 = tid & 7;
  const int sw0 = ((c0 ^ (r0 & 7)) << 3);

  // shuffle source lanes for P redistribution
  const int s0l = l15 + ((lh & 1) << 5);
  const int s1l = s0l + 16;

  const int nT = S >> 6;
  {
    gld16(khi + hb + r0 * 64 + sw0, (char*)Kh[0] + tid * 16);
    gld16(klo + hb + r0 * 64 + sw0, (char*)Kl[0] + tid * 16);
    gld16(vt + hb + (size_t)r0 * S + sw0, (char*)Vs[0] + tid * 16);
  }

  for (int kt = 0; kt < nT; ++kt) {
    __syncthreads();
    const int cb = kt & 1;
    if (kt + 1 < nT) {
      const int nb = cb ^ 1;
      const size_t kb = hb + (size_t)(kt + 1) * 64 * 64;
      gld16(khi + kb + r0 * 64 + sw0, (char*)Kh[nb] + tid * 16);
      gld16(klo + kb + r0 * 64 + sw0, (char*)Kl[nb] + tid * 16);
      const short* vg = vt + hb + (size_t)(kt + 1) * 64;
      gld16(vg + (size_t)r0 * S + sw0, (char*)Vs[nb] + tid * 16);
    }

    const short* KhB = Kh[cb];
    const short* KlB = Kl[cb];
    const short* VsB = Vs[cb];

    // swapped scores: accs[n][i] = score[key=16n+lh*4+i][query=l15]
    f32x4 accs[4];
#pragma unroll
    for (int n = 0; n < 4; ++n) accs[n] = (f32x4){0.f, 0.f, 0.f, 0.f};
    __builtin_amdgcn_s_setprio(1);
#pragma unroll
    for (int n = 0; n < 4; ++n) {
      const int row = n * 16 + l15;
      const int sw = row & 7;
      const int ro = row * 64;
      bf16x8 bh0 = *(const bf16x8*)&KhB[ro + ((lh ^ sw) << 3)];
      bf16x8 bh1 = *(const bf16x8*)&KhB[ro + (((4 + lh) ^ sw) << 3)];
      bf16x8 bl0 = *(const bf16x8*)&KlB[ro + ((lh ^ sw) << 3)];
      bf16x8 bl1 = *(const bf16x8*)&KlB[ro + (((4 + lh) ^ sw) << 3)];
      accs[n] = __builtin_amdgcn_mfma_f32_16x16x32_bf16(bh0, aqh[0], accs[n], 0, 0, 0);
      accs[n] = __builtin_amdgcn_mfma_f32_16x16x32_bf16(bh1, aqh[1], accs[n], 0, 0, 0);
      accs[n] = __builtin_amdgcn_mfma_f32_16x16x32_bf16(bl0, aqh[0], accs[n], 0, 0, 0);
      accs[n] = __builtin_amdgcn_mfma_f32_16x16x32_bf16(bl1, aqh[1], accs[n], 0, 0, 0);
      accs[n] = __builtin_amdgcn_mfma_f32_16x16x32_bf16(bh0, aql[0], accs[n], 0, 0, 0);
      accs[n] = __builtin_amdgcn_mfma_f32_16x16x32_bf16(bh1, aql[1], accs[n], 0, 0, 0);
    }
    __builtin_amdgcn_s_setprio(0);

    // local tile-max over this lane's 16 scores, then 2 shfls across lh
    float m01 = fmaxf(fmaxf(accs[0][0], accs[0][1]), fmaxf(accs[0][2], accs[0][3]));
    float m11 = fmaxf(fmaxf(accs[1][0], accs[1][1]), fmaxf(accs[1][2], accs[1][3]));
    float m21 = fmaxf(fmaxf(accs[2][0], accs[2][1]), fmaxf(accs[2][2], accs[2][3]));
    float m31 = fmaxf(fmaxf(accs[3][0], accs[3][1]), fmaxf(accs[3][2], accs[3][3]));
    float mt = fmaxf(fmaxf(m01, m11), fmaxf(m21, m31));
    mt = fmaxf(mt, __shfl_xor(mt, 16));
    mt = fmaxf(mt, __shfl_xor(mt, 32));  // query-uniform across lh groups

    // defer-max (THR=8)
    if (__any(mt > m_run + 8.f)) {
      float mn = fmaxf(m_run, mt);
      float a = __expf(m_run - mn);
      m_run = mn;
      l_run *= a;
      float a0 = __shfl(a, lh * 4 + 0);
      float a1 = __shfl(a, lh * 4 + 1);
      float a2 = __shfl(a, lh * 4 + 2);
      float a3 = __shfl(a, lh * 4 + 3);
#pragma unroll
      for (int n = 0; n < 4; ++n) {
        acc_o[n][0] *= a0; acc_o[n][1] *= a1;
        acc_o[n][2] *= a2; acc_o[n][3] *= a3;
      }
    }

    // p = exp(s - m); partial l; pack into dwords (keys 16n+4g+{i,i+1})
    unsigned int dw00, dw01, dw10, dw11, dw20, dw21, dw30, dw31;
    {
      float p0, p1, p2, p3;
      p0 = __expf(accs[0][0] - m_run); p1 = __expf(accs[0][1] - m_run);
      p2 = __expf(accs[0][2] - m_run); p3 = __expf(accs[0][3] - m_run);
      l_run += (p0 + p1) + (p2 + p3);
      dw00 = ((unsigned int)f2bf(p1) << 16) | f2bf(p0);
      dw01 = ((unsigned int)f2bf(p3) << 16) | f2bf(p2);
      p0 = __expf(accs[1][0] - m_run); p1 = __expf(accs[1][1] - m_run);
      p2 = __expf(accs[1][2] - m_run); p3 = __expf(accs[1][3] - m_run);
      l_run += (p0 + p1) + (p2 + p3);
      dw10 = ((unsigned int)f2bf(p1) << 16) | f2bf(p0);
      dw11 = ((unsigned int)f2bf(p3) << 16) | f2bf(p2);
      p0 = __expf(accs[2][0] - m_run); p1 = __expf(accs[2][1] - m_run);
      p2 = __expf(accs[2][2] - m_run); p3 = __expf(accs[2][3] - m_run);
      l_run += (p0 + p1) + (p2 + p3);
      dw20 = ((unsigned int)f2bf(p1) << 16) | f2bf(p0);
      dw21 = ((unsigned int)f2bf(p3) << 16) | f2bf(p2);
      p0 = __expf(accs[3][0] - m_run); p1 = __expf(accs[3][1] - m_run);
      p2 = __expf(accs[3][2] - m_run); p3 = __expf(accs[3][3] - m_run);
      l_run += (p0 + p1) + (p2 + p3);
      dw30 = ((unsigned int)f2bf(p1) << 16) | f2bf(p0);
      dw31 = ((unsigned int)f2bf(p3) << 16) | f2bf(p2);
    }

    // redistribute P: pa0 keys 8g+0..7 (n'=g>>1), pa1 keys 32+8g+0..7
    const bool lo2 = (lh < 2);
    unsigned int a0 = (unsigned int)__shfl((int)dw00, s0l);
    unsigned int a1 = (unsigned int)__shfl((int)dw01, s0l);
    unsigned int a2 = (unsigned int)__shfl((int)dw00, s1l);
    unsigned int a3 = (unsigned int)__shfl((int)dw01, s1l);
    unsigned int b0 = (unsigned int)__shfl((int)dw10, s0l);
    unsigned int b1 = (unsigned int)__shfl((int)dw11, s0l);
    unsigned int b2 = (unsigned int)__shfl((int)dw10, s1l);
    unsigned int b3 = (unsigned int)__shfl((int)dw11, s1l);
    u32x4 W0 = {lo2 ? a0 : b0, lo2 ? a1 : b1, lo2 ? a2 : b2, lo2 ? a3 : b3};
    unsigned int c0_ = (unsigned int)__shfl((int)dw20, s0l);
    unsigned int c1_ = (unsigned int)__shfl((int)dw21, s0l);
    unsigned int c2_ = (unsigned int)__shfl((int)dw20, s1l);
    unsigned int c3_ = (unsigned int)__shfl((int)dw21, s1l);
    unsigned int d0 = (unsigned int)__shfl((int)dw30, s0l);
    unsigned int d1 = (unsigned int)__shfl((int)dw31, s0l);
    unsigned int d2 = (unsigned int)__shfl((int)dw30, s1l);
    unsigned int d3 = (unsigned int)__shfl((int)dw31, s1l);
    u32x4 W1 = {lo2 ? c0_ : d0, lo2 ? c1_ : d1, lo2 ? c2_ : d2, lo2 ? c3_ : d3};
    bf16x8 pa0 = __builtin_bit_cast(bf16x8, W0);
    bf16x8 pa1 = __builtin_bit_cast(bf16x8, W1);

    __builtin_amdgcn_s_setprio(1);
#pragma unroll
    for (int n = 0; n < 4; ++n) {
      const int row = n * 16 + l15;
      const int sw = row & 7;
      const int ro = row * 64;
      bf16x8 bv0 = *(const bf16x8*)&VsB[ro + ((lh ^ sw) << 3)];
      bf16x8 bv1 = *(const bf16x8*)&VsB[ro + (((4 + lh) ^ sw) << 3)];
      acc_o[n] = __builtin_amdgcn_mfma_f32_16x16x32_bf16(pa0, bv0, acc_o[n], 0, 0, 0);
      acc_o[n] = __builtin_amdgcn_mfma_f32_16x16x32_bf16(pa1, bv1, acc_o[n], 0, 0, 0);
    }
    __builtin_amdgcn_s_setprio(0);
  }

  // total l per query: sum partials across lh groups, reciprocal, gather
  float lsum = l_run + __shfl_xor(l_run, 16);
  lsum += __shfl_xor(lsum, 32);
  float lrec = 1.0f / lsum;
  float r0i = __shfl(lrec, lh * 4 + 0);
  float r1i = __shfl(lrec, lh * 4 + 1);
  float r2i = __shfl(lrec, lh * 4 + 2);
  float r3i = __shfl(lrec, lh * 4 + 3);

  const int b = bh >> 4, h = bh & 15;
#pragma unroll
  for (int n = 0; n < 4; ++n) {
    const int dim = n * 16 + l15;
    const float rs[4] = {r0i, r1i, r2i, r3i};
#pragma unroll
    for (int i = 0; i < 4; ++i) {
      const int r = q0 + wid * 16 + lh * 4 + i;
      o[((size_t)(b * S + r)) * 1024 + h * 64 + dim] = f2bf(acc_o[n][i] * rs[i]);
    }
  }
}

// ---------------- launch ----------------

extern "C" void kernel_launch(void* const* d_in, const int* in_sizes, int n_in,
                              void* d_out, int out_size, void* d_ws,
                              size_t ws_size, hipStream_t stream) {
  const float* x = (const float*)d_in[0];
  const float* in_project = (const float*)d_in[1];
  const float* out_project = (const float*)d_in[2];
  const float* ln1_g = (const float*)d_in[3];
  const float* ln1_b = (const float*)d_in[4];
  const float* w_up = (const float*)d_in[5];
  const float* b_up = (const float*)d_in[6];
  const float* w_down = (const float*)d_in[7];
  const float* b_down = (const float*)d_in[8];
  const float* ln2_g = (const float*)d_in[9];
  const float* ln2_b = (const float*)d_in[10];

  const int B = in_sizes[0] / (1024 * 1024);
  const int S = 1024, H = 16;
  const int M = B * S;  // 4096

  char* ws = (char*)d_ws;
  short* h_hi = (short*)(ws + 0);                 // 8MB
  short* h_lo = (short*)(ws + 8388608);           // 8MB
  float* x2 = (float*)(ws + 0);                   // 16MB, reuses h (dead)
  short* qhi = (short*)(ws + 16777216);           // 8MB
  short* qlo = (short*)(ws + 25165824);           // 8MB
  short* khi = (short*)(ws + 33554432);           // 8MB
  short* klo = (short*)(ws + 41943040);           // 8MB
  short* vt  = (short*)(ws + 50331648);           // 8MB
  short* o = (short*)(ws + 67108864);             // 8MB
  short* h2 = (short*)(ws + 75497472);            // 8MB
  short* u = (short*)(ws + 83886080);             // 16MB
  short* Wq_hi = (short*)(ws + 100663296);        // 6MB
  short* Wq_lo = (short*)(ws + 106954752);        // 6MB
  short* WoT = (short*)(ws + 113246208);          // 2MB
  short* WupT = (short*)(ws + 115343360);         // 4MB
  short* WdnT = (short*)(ws + 119537664);         // 4MB

  cast_split_kernel<<<2048, 256, 0, stream>>>(in_project, (unsigned short*)Wq_hi,
                                              (unsigned short*)Wq_lo, 3072 * 1024);
  transpose3_kernel<<<dim3(64, 64, 3), dim3(32, 8), 0, stream>>>(
      out_project, w_up, w_down, (unsigned short*)WoT, (unsigned short*)WupT,
      (unsigned short*)WdnT);

  ln_kernel<true><<<M, 256, 0, stream>>>(x, ln1_g, ln1_b, (unsigned short*)h_hi,
                                         (unsigned short*)h_lo);

  // QK GEMM (split x3, N=2048) -> q/k split bf16
  gemm_kernel<true, false, false, false, false, 1>
      <<<dim3(2048 / 128, M / 128), 256, 0, stream>>>(
          h_hi, h_lo, Wq_hi, Wq_lo, nullptr, nullptr, nullptr, M, 2048, 1024,
          (unsigned short*)qhi, (unsigned short*)qlo, (unsigned short*)khi,
          (unsigned short*)klo, nullptr);

  // V GEMM (plain, N=1024) -> v^T bf16
  gemm_kernel<false, false, false, false, false, 2>
      <<<dim3(1024 / 128, M / 128), 256, 0, stream>>>(
          h_hi, nullptr, Wq_hi + (size_t)2048 * 1024, nullptr, nullptr, nullptr,
          nullptr, M, 1024, 1024, nullptr, nullptr, nullptr, nullptr,
          (unsigned short*)vt);

  attn_mfma_kernel<<<512, 512, 0, stream>>>(
      qhi, qlo, khi, klo, vt, (unsigned short*)o, S, H);

  gemm_kernel<false, false, true, false, false, 0>
      <<<dim3(1024 / 128, M / 128), 256, 0, stream>>>(
          o, nullptr, WoT, nullptr, nullptr, x, x2, M, 1024, 1024,
          nullptr, nullptr, nullptr, nullptr, nullptr);

  ln_kernel<false><<<M, 256, 0, stream>>>(x2, ln2_g, ln2_b,
                                          (unsigned short*)h2, nullptr);

  gemm_kernel<false, true, false, true, true, 0>
      <<<dim3(2048 / 128, M / 128), 256, 0, stream>>>(
          h2, nullptr, WupT, nullptr, b_up, nullptr, u, M, 2048, 1024,
          nullptr, nullptr, nullptr, nullptr, nullptr);

  gemm_kernel<false, true, true, false, false, 0>
      <<<dim3(1024 / 128, M / 128), 256, 0, stream>>>(
          u, nullptr, WdnT, nullptr, b_down, x2, d_out, M, 1024, 2048,
          nullptr, nullptr, nullptr, nullptr, nullptr);
}

// Round 7
// 254.266 us; speedup vs baseline: 1.0115x; 1.0115x over previous
//
#include <hip/hip_runtime.h>
#include <hip/hip_bf16.h>

// ---------------------------------------------------------------------------
// ResidualAttentionBlock: LN1 -> QKV -> MHA -> out-proj(+x) -> LN2 -> FFN(+x)
// B=4, S=1024, d=1024, H=16, dh=64.
//   - GEMMs: MFMA bf16, 128x128 tile, BK=32, global_load_lds, 2-phase LDS dbuf.
//   - QK GEMM (N=2048): split-bf16 (hi+lo) x3 MFMA -> Q(x0.125),K split bf16.
//   - V GEMM (N=1024): plain bf16 -> V transposed [b,h,dim,key].
//   - Attention: 32x32x16 MFMA flash, swapped QK^T, XCD-aware grid.
//     P redistribution = 16 cvt-pack + 8 permlane32_swap (pure VALU half-swap;
//     shfl_xor(32) fallback). 4 waves x 32q, 48KB LDS.
// ---------------------------------------------------------------------------

typedef short bf16x8 __attribute__((ext_vector_type(8)));
typedef float f32x4 __attribute__((ext_vector_type(4)));
typedef float f32x16 __attribute__((ext_vector_type(16)));

__device__ __forceinline__ unsigned short f2bf(float f) {
  unsigned int u = __float_as_uint(f);
  unsigned int r = (u + 0x7fffu + ((u >> 16) & 1u)) >> 16;
  return (unsigned short)r;
}
__device__ __forceinline__ float bf2f(unsigned short h) {
  return __uint_as_float(((unsigned int)h) << 16);
}
__device__ __forceinline__ unsigned pack2(float x, float y) {
  return ((unsigned)f2bf(y) << 16) | f2bf(x);
}

__device__ __forceinline__ void gld16(const void* g, void* l) {
  __builtin_amdgcn_global_load_lds(
      (const __attribute__((address_space(1))) unsigned int*)g,
      (__attribute__((address_space(3))) unsigned int*)l, 16, 0, 0);
}

#if defined(__has_builtin)
#if __has_builtin(__builtin_amdgcn_permlane32_swap)
#define HAVE_PLSWAP 1
#endif
#endif

// After plswap(a,b): a' = [a(lanes0-31) | b(from lanes0-31)],
//                    b' = [a(from lanes32-63) | b(lanes32-63)]
__device__ __forceinline__ void plswap(unsigned& a, unsigned& b) {
#ifdef HAVE_PLSWAP
  auto r = __builtin_amdgcn_permlane32_swap(a, b, 0, 0);
  a = r[0];
  b = r[1];
#else
  unsigned ta = (unsigned)__shfl_xor((int)a, 32);
  unsigned tb = (unsigned)__shfl_xor((int)b, 32);
  bool hi = (threadIdx.x & 32) != 0;
  unsigned na = hi ? tb : a;
  unsigned nb = hi ? b : ta;
  a = na;
  b = nb;
#endif
}

// ---------------- weight prep ----------------

__global__ void cast_split_kernel(const float* __restrict__ in,
                                  unsigned short* __restrict__ hi,
                                  unsigned short* __restrict__ lo, int n) {
  int i = blockIdx.x * blockDim.x + threadIdx.x;
  int stride = gridDim.x * blockDim.x;
  for (; i < n; i += stride) {
    float v = in[i];
    unsigned short h = f2bf(v);
    hi[i] = h;
    lo[i] = f2bf(v - bf2f(h));
  }
}

// three transposes in one launch (z selects matrix)
__global__ void transpose3_kernel(const float* __restrict__ op,
                                  const float* __restrict__ wu,
                                  const float* __restrict__ wd,
                                  unsigned short* __restrict__ oT,
                                  unsigned short* __restrict__ uT,
                                  unsigned short* __restrict__ dT) {
  const float* in;
  unsigned short* out;
  int R, C;
  if (blockIdx.z == 0) { in = op; out = oT; R = 1024; C = 1024; }
  else if (blockIdx.z == 1) { in = wu; out = uT; R = 1024; C = 2048; }
  else { in = wd; out = dT; R = 2048; C = 1024; }
  int bc = blockIdx.x << 5;
  int br = blockIdx.y << 5;
  if (bc >= C || br >= R) return;
  __shared__ float t[32][33];
  int tx = threadIdx.x, ty = threadIdx.y;
#pragma unroll
  for (int i = ty; i < 32; i += 8)
    t[i][tx] = in[(size_t)(br + i) * C + bc + tx];
  __syncthreads();
#pragma unroll
  for (int i = ty; i < 32; i += 8)
    out[(size_t)(bc + i) * R + br + tx] = f2bf(t[tx][i]);
}

// ---------------- layernorm (d=1024 fixed) ----------------

template <bool SPLIT>
__global__ __launch_bounds__(256) void ln_kernel(
    const float* __restrict__ x, const float* __restrict__ gamma,
    const float* __restrict__ beta, unsigned short* __restrict__ hi,
    unsigned short* __restrict__ lo) {
  int row = blockIdx.x, tid = threadIdx.x;
  float4 v = ((const float4*)x)[(size_t)row * 256 + tid];
  float s = v.x + v.y + v.z + v.w;
  float ss = v.x * v.x + v.y * v.y + v.z * v.z + v.w * v.w;
#pragma unroll
  for (int off = 32; off; off >>= 1) {
    s += __shfl_xor(s, off);
    ss += __shfl_xor(ss, off);
  }
  __shared__ float red[8];
  int wid = tid >> 6, lane = tid & 63;
  if (lane == 0) { red[wid] = s; red[4 + wid] = ss; }
  __syncthreads();
  s = red[0] + red[1] + red[2] + red[3];
  ss = red[4] + red[5] + red[6] + red[7];
  float mean = s * (1.f / 1024.f);
  float var = ss * (1.f / 1024.f) - mean * mean;
  float inv = rsqrtf(var + 1e-5f);
  float4 g = ((const float4*)gamma)[tid];
  float4 bt = ((const float4*)beta)[tid];
  float y[4];
  y[0] = (v.x - mean) * inv * g.x + bt.x;
  y[1] = (v.y - mean) * inv * g.y + bt.y;
  y[2] = (v.z - mean) * inv * g.z + bt.z;
  y[3] = (v.w - mean) * inv * g.w + bt.w;
  size_t o = (size_t)row * 1024 + tid * 4;
#pragma unroll
  for (int j = 0; j < 4; ++j) {
    unsigned short hb = f2bf(y[j]);
    hi[o + j] = hb;
    if (SPLIT) lo[o + j] = f2bf(y[j] - bf2f(hb));
  }
}

// ---------------- GEMM: C[M,N] = A[M,K] * W[N,K]^T ----------------
// bf16 MFMA 16x16x32, tile 128x128, BK=32, 4 waves, 2-phase LDS dbuf.
// OUTMODE: 0 normal, 1 QK-split epilogue (N=2048), 2 V-transpose epilogue.

template <bool SPLIT, bool BIAS, bool RESID, bool RELU, bool OUTBF16,
          int OUTMODE>
__global__ __launch_bounds__(256) void gemm_kernel(
    const short* __restrict__ Ah, const short* __restrict__ Al,
    const short* __restrict__ Bh, const short* __restrict__ Bl,
    const float* __restrict__ bias, const float* __restrict__ resid,
    void* __restrict__ outp, int M, int N, int K,
    unsigned short* __restrict__ qh, unsigned short* __restrict__ ql,
    unsigned short* __restrict__ kh, unsigned short* __restrict__ kl,
    unsigned short* __restrict__ vtp) {
  __shared__ short As[2][128 * 32];
  __shared__ short Bs[2][128 * 32];
  __shared__ short As2[SPLIT ? 2 : 1][SPLIT ? 128 * 32 : 8];
  __shared__ short Bs2[SPLIT ? 2 : 1][SPLIT ? 128 * 32 : 8];

  const int tid = threadIdx.x;
  const int lane = tid & 63;
  const int wid = tid >> 6;
  const int wr = (wid >> 1) << 6;
  const int wc = (wid & 1) << 6;
  const int l15 = lane & 15, lh = lane >> 4;
  const int rowBase = blockIdx.y << 7;
  const int colBase = blockIdx.x << 7;

  const int sr = tid >> 2;
  const int sc = (tid & 3) << 3;
  const int soff = sr * 32 + sc;
  const short* Ag = Ah + (size_t)(rowBase + sr) * K + sc;
  const short* Bg = Bh + (size_t)(colBase + sr) * K + sc;
  const short* Ag2 = SPLIT ? Al + (size_t)(rowBase + sr) * K + sc : nullptr;
  const short* Bg2 = SPLIT ? Bl + (size_t)(colBase + sr) * K + sc : nullptr;

  f32x4 acc[4][4];
#pragma unroll
  for (int m = 0; m < 4; ++m)
#pragma unroll
    for (int n = 0; n < 4; ++n) acc[m][n] = (f32x4){0.f, 0.f, 0.f, 0.f};

  const int kT = K >> 5;
  {
    gld16(Ag, &As[0][soff]);
    gld16(Ag + (size_t)64 * K, &As[0][soff + 64 * 32]);
    gld16(Bg, &Bs[0][soff]);
    gld16(Bg + (size_t)64 * K, &Bs[0][soff + 64 * 32]);
    if constexpr (SPLIT) {
      gld16(Ag2, &As2[0][soff]);
      gld16(Ag2 + (size_t)64 * K, &As2[0][soff + 64 * 32]);
      gld16(Bg2, &Bs2[0][soff]);
      gld16(Bg2 + (size_t)64 * K, &Bs2[0][soff + 64 * 32]);
    }
  }

  for (int kt = 0; kt < kT; ++kt) {
    __syncthreads();
    const int cb = kt & 1;
    if (kt + 1 < kT) {
      const int nb = cb ^ 1;
      const int k0 = (kt + 1) << 5;
      gld16(Ag + k0, &As[nb][soff]);
      gld16(Ag + k0 + (size_t)64 * K, &As[nb][soff + 64 * 32]);
      gld16(Bg + k0, &Bs[nb][soff]);
      gld16(Bg + k0 + (size_t)64 * K, &Bs[nb][soff + 64 * 32]);
      if constexpr (SPLIT) {
        gld16(Ag2 + k0, &As2[nb][soff]);
        gld16(Ag2 + k0 + (size_t)64 * K, &As2[nb][soff + 64 * 32]);
        gld16(Bg2 + k0, &Bs2[nb][soff]);
        gld16(Bg2 + k0 + (size_t)64 * K, &Bs2[nb][soff + 64 * 32]);
      }
    }

    const short* Asb = As[cb];
    const short* Bsb = Bs[cb];
    bf16x8 af[4], bfr[4];
#pragma unroll
    for (int m = 0; m < 4; ++m)
      af[m] = *(const bf16x8*)&Asb[(wr + m * 16 + l15) * 32 + lh * 8];
#pragma unroll
    for (int n = 0; n < 4; ++n)
      bfr[n] = *(const bf16x8*)&Bsb[(wc + n * 16 + l15) * 32 + lh * 8];
    if constexpr (SPLIT) {
      const short* Asb2 = As2[cb];
      const short* Bsb2 = Bs2[cb];
      bf16x8 af2[4], bfr2[4];
#pragma unroll
      for (int m = 0; m < 4; ++m)
        af2[m] = *(const bf16x8*)&Asb2[(wr + m * 16 + l15) * 32 + lh * 8];
#pragma unroll
      for (int n = 0; n < 4; ++n)
        bfr2[n] = *(const bf16x8*)&Bsb2[(wc + n * 16 + l15) * 32 + lh * 8];
#pragma unroll
      for (int m = 0; m < 4; ++m)
#pragma unroll
        for (int n = 0; n < 4; ++n) {
          acc[m][n] = __builtin_amdgcn_mfma_f32_16x16x32_bf16(af[m], bfr[n], acc[m][n], 0, 0, 0);
          acc[m][n] = __builtin_amdgcn_mfma_f32_16x16x32_bf16(af[m], bfr2[n], acc[m][n], 0, 0, 0);
          acc[m][n] = __builtin_amdgcn_mfma_f32_16x16x32_bf16(af2[m], bfr[n], acc[m][n], 0, 0, 0);
        }
    } else {
#pragma unroll
      for (int m = 0; m < 4; ++m)
#pragma unroll
        for (int n = 0; n < 4; ++n)
          acc[m][n] = __builtin_amdgcn_mfma_f32_16x16x32_bf16(af[m], bfr[n], acc[m][n], 0, 0, 0);
    }
  }

  const int prow = rowBase + wr + lh * 4;
  const int pcol = colBase + wc + l15;
#pragma unroll
  for (int m = 0; m < 4; ++m) {
#pragma unroll
    for (int n = 0; n < 4; ++n) {
      const int c = pcol + n * 16;
      float badd = 0.f;
      if constexpr (BIAS) badd = bias[c];
#pragma unroll
      for (int i = 0; i < 4; ++i) {
        const int r = prow + m * 16 + i;
        float v = acc[m][n][i] + badd;
        if constexpr (OUTMODE == 1) {
          const int part = c >> 10;
          const int cc = c & 1023;
          const int head = cc >> 6, dim = cc & 63;
          const int b = r >> 10, s = r & 1023;
          size_t idx = (((size_t)(b * 16 + head)) * 1024 + s) * 64 + dim;
          if (part == 0) {
            float y = v * 0.125f;
            unsigned short hb = f2bf(y);
            qh[idx] = hb;
            ql[idx] = f2bf(y - bf2f(hb));
          } else {
            unsigned short hb = f2bf(v);
            kh[idx] = hb;
            kl[idx] = f2bf(v - bf2f(hb));
          }
        } else if constexpr (OUTMODE == 2) {
          const int head = c >> 6, dim = c & 63;
          const int b = r >> 10, s = r & 1023;
          vtp[(((size_t)(b * 16 + head)) * 64 + dim) * 1024 + s] = f2bf(v);
        } else {
          if constexpr (RESID) v += resid[(size_t)r * N + c];
          if constexpr (RELU) v = fmaxf(v, 0.f);
          if constexpr (OUTBF16)
            ((unsigned short*)outp)[(size_t)r * N + c] = f2bf(v);
          else
            ((float*)outp)[(size_t)r * N + c] = v;
        }
      }
    }
  }
}

// ---------------- attention: 32x32x16 MFMA flash ----------------
// 512 blocks x 256 threads (4 waves x 32 q). XCD decode: blk&7 = xcd slot.
// Swapped QK: D = mfma(K, Q): lane (q=lane&31, hi=lane>>5) holds 16 scores
// per 32-key subtile (keys {4hi+i, 8+4hi+i, 16+4hi+i, 24+4hi+i}).
// P -> PV A-frag (lane needs keys 8hi+0..7 per 16-chunk) is exactly a
// lane<->lane+32 half swap: 16 cvt-pack + 8 permlane32_swap per 64-key tile.
// Softmax: local 31-fmax + 1 swap; l_run per-lane (q-indexed), 1 swap at end.

__global__ __launch_bounds__(256, 2) void attn_mfma_kernel(
    const short* __restrict__ qhi, const short* __restrict__ qlo,
    const short* __restrict__ khi, const short* __restrict__ klo,
    const short* __restrict__ vt, unsigned short* __restrict__ o,
    int S, int H) {
  __shared__ short Kh[2][64 * 64];
  __shared__ short Kl[2][64 * 64];
  __shared__ short Vs[2][64 * 64];

  const int tid = threadIdx.x, lane = tid & 63, wid = tid >> 6;
  const int l31 = lane & 31;
  const int hi = lane >> 5;
  const int blk = blockIdx.x;
  const int j = blk >> 3;
  const int bh = ((blk & 7) << 3) + (j & 7);
  const int q0 = (j >> 3) << 7;
  const size_t hbase = (size_t)bh * S * 64;

  // Q B-frags: lane (q = l31, hi): per kstep t needs Q[q][16t + 8hi + 0..7]
  const size_t qrow = hbase + (size_t)(q0 + wid * 32 + l31) * 64;
  bf16x8 qfh[4], qfl[4];
#pragma unroll
  for (int t = 0; t < 4; ++t) {
    qfh[t] = *(const bf16x8*)(qhi + qrow + t * 16 + hi * 8);
    qfl[t] = *(const bf16x8*)(qlo + qrow + t * 16 + hi * 8);
  }

  float m_run = -INFINITY, l_run = 0.f;
  f32x16 accO0, accO1;  // O[q-rows][dims l31], [dims 32+l31]
#pragma unroll
  for (int r = 0; r < 16; ++r) { accO0[r] = 0.f; accO1[r] = 0.f; }

  // staging: 256 threads, 512 chunks/array: thread covers chunks tid, tid+256
  const int r0 = tid >> 3, c0 = tid & 7;
  const int sw0 = ((c0 ^ (r0 & 7)) << 3);
  const int r1 = r0 + 32;
  const int sw1 = ((c0 ^ (r1 & 7)) << 3);

  const int nT = S >> 6;
  {
    gld16(khi + hbase + r0 * 64 + sw0, (char*)Kh[0] + tid * 16);
    gld16(khi + hbase + r1 * 64 + sw1, (char*)Kh[0] + tid * 16 + 4096);
    gld16(klo + hbase + r0 * 64 + sw0, (char*)Kl[0] + tid * 16);
    gld16(klo + hbase + r1 * 64 + sw1, (char*)Kl[0] + tid * 16 + 4096);
    gld16(vt + hbase + (size_t)r0 * S + sw0, (char*)Vs[0] + tid * 16);
    gld16(vt + hbase + (size_t)r1 * S + sw1, (char*)Vs[0] + tid * 16 + 4096);
  }

  for (int kt = 0; kt < nT; ++kt) {
    __syncthreads();
    const int cb = kt & 1;
    if (kt + 1 < nT) {
      const int nb = cb ^ 1;
      const size_t kb = hbase + (size_t)(kt + 1) * 64 * 64;
      gld16(khi + kb + r0 * 64 + sw0, (char*)Kh[nb] + tid * 16);
      gld16(khi + kb + r1 * 64 + sw1, (char*)Kh[nb] + tid * 16 + 4096);
      gld16(klo + kb + r0 * 64 + sw0, (char*)Kl[nb] + tid * 16);
      gld16(klo + kb + r1 * 64 + sw1, (char*)Kl[nb] + tid * 16 + 4096);
      const short* vg = vt + hbase + (size_t)(kt + 1) * 64;
      gld16(vg + (size_t)r0 * S + sw0, (char*)Vs[nb] + tid * 16);
      gld16(vg + (size_t)r1 * S + sw1, (char*)Vs[nb] + tid * 16 + 4096);
    }

    const short* KhB = Kh[cb];
    const short* KlB = Kl[cb];
    const short* VsB = Vs[cb];

    // QK: sA = keys 0-31 (A rows = l31), sB = keys 32-63 (rows 32+l31)
    f32x16 sA, sB;
#pragma unroll
    for (int r = 0; r < 16; ++r) { sA[r] = 0.f; sB[r] = 0.f; }
    __builtin_amdgcn_s_setprio(1);
#pragma unroll
    for (int t = 0; t < 4; ++t) {
      const int cA = ((2 * t + hi) ^ (l31 & 7)) << 3;
      bf16x8 kh0 = *(const bf16x8*)&KhB[l31 * 64 + cA];
      bf16x8 kl0 = *(const bf16x8*)&KlB[l31 * 64 + cA];
      bf16x8 kh1 = *(const bf16x8*)&KhB[(32 + l31) * 64 + cA];
      bf16x8 kl1 = *(const bf16x8*)&KlB[(32 + l31) * 64 + cA];
      sA = __builtin_amdgcn_mfma_f32_32x32x16_bf16(kh0, qfh[t], sA, 0, 0, 0);
      sB = __builtin_amdgcn_mfma_f32_32x32x16_bf16(kh1, qfh[t], sB, 0, 0, 0);
      sA = __builtin_amdgcn_mfma_f32_32x32x16_bf16(kh0, qfl[t], sA, 0, 0, 0);
      sB = __builtin_amdgcn_mfma_f32_32x32x16_bf16(kh1, qfl[t], sB, 0, 0, 0);
      sA = __builtin_amdgcn_mfma_f32_32x32x16_bf16(kl0, qfh[t], sA, 0, 0, 0);
      sB = __builtin_amdgcn_mfma_f32_32x32x16_bf16(kl1, qfh[t], sB, 0, 0, 0);
    }
    __builtin_amdgcn_s_setprio(0);

    // tile max: local over 32 regs, then one half-swap combine
    float mt = fmaxf(sA[0], sB[0]);
#pragma unroll
    for (int r = 1; r < 16; ++r) mt = fmaxf(mt, fmaxf(sA[r], sB[r]));
    {
      unsigned ma = __float_as_uint(mt), mb = ma;
      plswap(ma, mb);
      mt = fmaxf(__uint_as_float(ma), __uint_as_float(mb));
    }

    // defer-max (THR=8)
    if (__any(mt > m_run + 8.f)) {
      float mn = fmaxf(m_run, mt);
      float a = __expf(m_run - mn);
      m_run = mn;
      l_run *= a;
#pragma unroll
      for (int r = 0; r < 16; ++r) {
        const int qq = (r & 3) + 8 * (r >> 2) + 4 * hi;
        float ar = __shfl(a, qq);
        accO0[r] *= ar;
        accO1[r] *= ar;
      }
    }

    // p = exp(s - m); partial l; pack; half-swap into PV A-frags
    float pA[16], pB[16];
#pragma unroll
    for (int r = 0; r < 16; ++r) {
      pA[r] = __expf(sA[r] - m_run);
      pB[r] = __expf(sB[r] - m_run);
    }
    float ls = 0.f;
#pragma unroll
    for (int r = 0; r < 16; ++r) ls += pA[r] + pB[r];
    l_run += ls;

    // chunk 0 (keys 0-15): regs 0-7 of sA
    unsigned a0 = pack2(pA[0], pA[1]), a1 = pack2(pA[2], pA[3]);
    unsigned a2 = pack2(pA[4], pA[5]), a3 = pack2(pA[6], pA[7]);
    plswap(a0, a2);
    plswap(a1, a3);
    // chunk 1 (keys 16-31): regs 8-15 of sA
    unsigned b0 = pack2(pA[8], pA[9]), b1 = pack2(pA[10], pA[11]);
    unsigned b2 = pack2(pA[12], pA[13]), b3 = pack2(pA[14], pA[15]);
    plswap(b0, b2);
    plswap(b1, b3);
    // chunks 2,3 (keys 32-63): sB
    unsigned c0_ = pack2(pB[0], pB[1]), c1_ = pack2(pB[2], pB[3]);
    unsigned c2_ = pack2(pB[4], pB[5]), c3_ = pack2(pB[6], pB[7]);
    plswap(c0_, c2_);
    plswap(c1_, c3_);
    unsigned d0 = pack2(pB[8], pB[9]), d1 = pack2(pB[10], pB[11]);
    unsigned d2 = pack2(pB[12], pB[13]), d3 = pack2(pB[14], pB[15]);
    plswap(d0, d2);
    plswap(d1, d3);

    bf16x8 pf0, pf1, pf2, pf3;
    {
      unsigned w[4];
      w[0] = a0; w[1] = a1; w[2] = a2; w[3] = a3;
      pf0 = *(bf16x8*)w;
      w[0] = b0; w[1] = b1; w[2] = b2; w[3] = b3;
      pf1 = *(bf16x8*)w;
      w[0] = c0_; w[1] = c1_; w[2] = c2_; w[3] = c3_;
      pf2 = *(bf16x8*)w;
      w[0] = d0; w[1] = d1; w[2] = d2; w[3] = d3;
      pf3 = *(bf16x8*)w;
    }

    // PV: acc0 (dims l31), acc1 (dims 32+l31); B-frag from Vs row=dim,
    // key chunk c: byte col ((2c+hi)^(dim&7))<<4
    __builtin_amdgcn_s_setprio(1);
    {
      const int sw_a = ((l31 & 7)) ;  // dim0 = l31
      const int d1r = 32 + l31;
#pragma unroll
      for (int c = 0; c < 4; ++c) {
        bf16x8 bv0 = *(const bf16x8*)&VsB[l31 * 64 + ((((2 * c + hi)) ^ (l31 & 7)) << 3)];
        bf16x8 bv1 = *(const bf16x8*)&VsB[d1r * 64 + ((((2 * c + hi)) ^ (d1r & 7)) << 3)];
        bf16x8 pf = (c == 0) ? pf0 : (c == 1) ? pf1 : (c == 2) ? pf2 : pf3;
        accO0 = __builtin_amdgcn_mfma_f32_32x32x16_bf16(pf, bv0, accO0, 0, 0, 0);
        accO1 = __builtin_amdgcn_mfma_f32_32x32x16_bf16(pf, bv1, accO1, 0, 0, 0);
      }
    }
    __builtin_amdgcn_s_setprio(0);
  }

  // total l per q (= l31): one half-swap combine, then gather per acc row
  {
    unsigned la = __float_as_uint(l_run), lb = la;
    plswap(la, lb);
    l_run = __uint_as_float(la) + __uint_as_float(lb);
  }
  float lrec = 1.0f / l_run;

  const int b = bh >> 4, h = bh & 15;
#pragma unroll
  for (int r = 0; r < 16; ++r) {
    const int qq = (r & 3) + 8 * (r >> 2) + 4 * hi;
    float rr = __shfl(lrec, qq);
    const size_t row = (size_t)(b * S + q0 + wid * 32 + qq) * 1024 + h * 64;
    o[row + l31] = f2bf(accO0[r] * rr);
    o[row + 32 + l31] = f2bf(accO1[r] * rr);
  }
}

// ---------------- launch ----------------

extern "C" void kernel_launch(void* const* d_in, const int* in_sizes, int n_in,
                              void* d_out, int out_size, void* d_ws,
                              size_t ws_size, hipStream_t stream) {
  const float* x = (const float*)d_in[0];
  const float* in_project = (const float*)d_in[1];
  const float* out_project = (const float*)d_in[2];
  const float* ln1_g = (const float*)d_in[3];
  const float* ln1_b = (const float*)d_in[4];
  const float* w_up = (const float*)d_in[5];
  const float* b_up = (const float*)d_in[6];
  const float* w_down = (const float*)d_in[7];
  const float* b_down = (const float*)d_in[8];
  const float* ln2_g = (const float*)d_in[9];
  const float* ln2_b = (const float*)d_in[10];

  const int B = in_sizes[0] / (1024 * 1024);
  const int S = 1024, H = 16;
  const int M = B * S;  // 4096

  char* ws = (char*)d_ws;
  short* h_hi = (short*)(ws + 0);                 // 8MB
  short* h_lo = (short*)(ws + 8388608);           // 8MB
  float* x2 = (float*)(ws + 0);                   // 16MB, reuses h (dead)
  short* qhi = (short*)(ws + 16777216);           // 8MB
  short* qlo = (short*)(ws + 25165824);           // 8MB
  short* khi = (short*)(ws + 33554432);           // 8MB
  short* klo = (short*)(ws + 41943040);           // 8MB
  short* vt  = (short*)(ws + 50331648);           // 8MB
  short* o = (short*)(ws + 67108864);             // 8MB
  short* h2 = (short*)(ws + 75497472);            // 8MB
  short* u = (short*)(ws + 83886080);             // 16MB
  short* Wq_hi = (short*)(ws + 100663296);        // 6MB
  short* Wq_lo = (short*)(ws + 106954752);        // 6MB
  short* WoT = (short*)(ws + 113246208);          // 2MB
  short* WupT = (short*)(ws + 115343360);         // 4MB
  short* WdnT = (short*)(ws + 119537664);         // 4MB

  cast_split_kernel<<<2048, 256, 0, stream>>>(in_project, (unsigned short*)Wq_hi,
                                              (unsigned short*)Wq_lo, 3072 * 1024);
  transpose3_kernel<<<dim3(64, 64, 3), dim3(32, 8), 0, stream>>>(
      out_project, w_up, w_down, (unsigned short*)WoT, (unsigned short*)WupT,
      (unsigned short*)WdnT);

  ln_kernel<true><<<M, 256, 0, stream>>>(x, ln1_g, ln1_b, (unsigned short*)h_hi,
                                         (unsigned short*)h_lo);

  // QK GEMM (split x3, N=2048) -> q/k split bf16
  gemm_kernel<true, false, false, false, false, 1>
      <<<dim3(2048 / 128, M / 128), 256, 0, stream>>>(
          h_hi, h_lo, Wq_hi, Wq_lo, nullptr, nullptr, nullptr, M, 2048, 1024,
          (unsigned short*)qhi, (unsigned short*)qlo, (unsigned short*)khi,
          (unsigned short*)klo, nullptr);

  // V GEMM (plain, N=1024) -> v^T bf16
  gemm_kernel<false, false, false, false, false, 2>
      <<<dim3(1024 / 128, M / 128), 256, 0, stream>>>(
          h_hi, nullptr, Wq_hi + (size_t)2048 * 1024, nullptr, nullptr, nullptr,
          nullptr, M, 1024, 1024, nullptr, nullptr, nullptr, nullptr,
          (unsigned short*)vt);

  attn_mfma_kernel<<<512, 256, 0, stream>>>(
      qhi, qlo, khi, klo, vt, (unsigned short*)o, S, H);

  gemm_kernel<false, false, true, false, false, 0>
      <<<dim3(1024 / 128, M / 128), 256, 0, stream>>>(
          o, nullptr, WoT, nullptr, nullptr, x, x2, M, 1024, 1024,
          nullptr, nullptr, nullptr, nullptr, nullptr);

  ln_kernel<false><<<M, 256, 0, stream>>>(x2, ln2_g, ln2_b,
                                          (unsigned short*)h2, nullptr);

  gemm_kernel<false, true, false, true, true, 0>
      <<<dim3(2048 / 128, M / 128), 256, 0, stream>>>(
          h2, nullptr, WupT, nullptr, b_up, nullptr, u, M, 2048, 1024,
          nullptr, nullptr, nullptr, nullptr, nullptr);

  gemm_kernel<false, true, true, false, false, 0>
      <<<dim3(1024 / 128, M / 128), 256, 0, stream>>>(
          u, nullptr, WdnT, nullptr, b_down, x2, d_out, M, 1024, 2048,
          nullptr, nullptr, nullptr, nullptr, nullptr);
}

// Round 8
// 246.562 us; speedup vs baseline: 1.0431x; 1.0312x over previous
//
#include <hip/hip_runtime.h>
#include <hip/hip_bf16.h>

// ---------------------------------------------------------------------------
// ResidualAttentionBlock: LN1 -> QKV -> MHA -> out-proj(+x) -> LN2 -> FFN(+x)
// B=4, S=1024, d=1024, H=16, dh=64.
//   - GEMMs: MFMA bf16, 128x128 tile, BK=32, global_load_lds, 2-phase LDS dbuf.
//   - QK GEMM (N=2048): split-bf16 x3 MFMA -> Q(x0.125*log2e), K split bf16.
//   - V GEMM (N=1024): plain bf16 -> V transposed [b,h,dim,key].
//   - Attention: 32x32x16 MFMA flash, swapped QK^T, exp2-domain softmax,
//     v_perm trunc-pack P, permlane32_swap redistribution, 3 blocks/CU.
// ---------------------------------------------------------------------------

typedef short bf16x8 __attribute__((ext_vector_type(8)));
typedef float f32x4 __attribute__((ext_vector_type(4)));
typedef float f32x16 __attribute__((ext_vector_type(16)));

__device__ __forceinline__ unsigned short f2bf(float f) {
  unsigned int u = __float_as_uint(f);
  unsigned int r = (u + 0x7fffu + ((u >> 16) & 1u)) >> 16;
  return (unsigned short)r;
}
__device__ __forceinline__ float bf2f(unsigned short h) {
  return __uint_as_float(((unsigned int)h) << 16);
}
// truncating pack of two f32 -> 2xbf16 in one v_perm_b32
__device__ __forceinline__ unsigned pack2t(float x, float y) {
  return __builtin_amdgcn_perm(__float_as_uint(y), __float_as_uint(x),
                               0x07060302u);
}
__device__ __forceinline__ float fexp2(float x) {
#if defined(__has_builtin)
#if __has_builtin(__builtin_amdgcn_exp2f)
  return __builtin_amdgcn_exp2f(x);
#else
  return exp2f(x);
#endif
#else
  return exp2f(x);
#endif
}

__device__ __forceinline__ void gld16(const void* g, void* l) {
  __builtin_amdgcn_global_load_lds(
      (const __attribute__((address_space(1))) unsigned int*)g,
      (__attribute__((address_space(3))) unsigned int*)l, 16, 0, 0);
}

#if defined(__has_builtin)
#if __has_builtin(__builtin_amdgcn_permlane32_swap)
#define HAVE_PLSWAP 1
#endif
#endif

__device__ __forceinline__ void plswap(unsigned& a, unsigned& b) {
#ifdef HAVE_PLSWAP
  auto r = __builtin_amdgcn_permlane32_swap(a, b, 0, 0);
  a = r[0];
  b = r[1];
#else
  unsigned ta = (unsigned)__shfl_xor((int)a, 32);
  unsigned tb = (unsigned)__shfl_xor((int)b, 32);
  bool hi = (threadIdx.x & 32) != 0;
  unsigned na = hi ? tb : a;
  unsigned nb = hi ? b : ta;
  a = na;
  b = nb;
#endif
}

// ---------------- weight prep ----------------

__global__ void cast_split_kernel(const float* __restrict__ in,
                                  unsigned short* __restrict__ hi,
                                  unsigned short* __restrict__ lo, int n) {
  int i = blockIdx.x * blockDim.x + threadIdx.x;
  int stride = gridDim.x * blockDim.x;
  for (; i < n; i += stride) {
    float v = in[i];
    unsigned short h = f2bf(v);
    hi[i] = h;
    lo[i] = f2bf(v - bf2f(h));
  }
}

__global__ void transpose3_kernel(const float* __restrict__ op,
                                  const float* __restrict__ wu,
                                  const float* __restrict__ wd,
                                  unsigned short* __restrict__ oT,
                                  unsigned short* __restrict__ uT,
                                  unsigned short* __restrict__ dT) {
  const float* in;
  unsigned short* out;
  int R, C;
  if (blockIdx.z == 0) { in = op; out = oT; R = 1024; C = 1024; }
  else if (blockIdx.z == 1) { in = wu; out = uT; R = 1024; C = 2048; }
  else { in = wd; out = dT; R = 2048; C = 1024; }
  int bc = blockIdx.x << 5;
  int br = blockIdx.y << 5;
  if (bc >= C || br >= R) return;
  __shared__ float t[32][33];
  int tx = threadIdx.x, ty = threadIdx.y;
#pragma unroll
  for (int i = ty; i < 32; i += 8)
    t[i][tx] = in[(size_t)(br + i) * C + bc + tx];
  __syncthreads();
#pragma unroll
  for (int i = ty; i < 32; i += 8)
    out[(size_t)(bc + i) * R + br + tx] = f2bf(t[tx][i]);
}

// ---------------- layernorm (d=1024 fixed) ----------------

template <bool SPLIT>
__global__ __launch_bounds__(256) void ln_kernel(
    const float* __restrict__ x, const float* __restrict__ gamma,
    const float* __restrict__ beta, unsigned short* __restrict__ hi,
    unsigned short* __restrict__ lo) {
  int row = blockIdx.x, tid = threadIdx.x;
  float4 v = ((const float4*)x)[(size_t)row * 256 + tid];
  float s = v.x + v.y + v.z + v.w;
  float ss = v.x * v.x + v.y * v.y + v.z * v.z + v.w * v.w;
#pragma unroll
  for (int off = 32; off; off >>= 1) {
    s += __shfl_xor(s, off);
    ss += __shfl_xor(ss, off);
  }
  __shared__ float red[8];
  int wid = tid >> 6, lane = tid & 63;
  if (lane == 0) { red[wid] = s; red[4 + wid] = ss; }
  __syncthreads();
  s = red[0] + red[1] + red[2] + red[3];
  ss = red[4] + red[5] + red[6] + red[7];
  float mean = s * (1.f / 1024.f);
  float var = ss * (1.f / 1024.f) - mean * mean;
  float inv = rsqrtf(var + 1e-5f);
  float4 g = ((const float4*)gamma)[tid];
  float4 bt = ((const float4*)beta)[tid];
  float y[4];
  y[0] = (v.x - mean) * inv * g.x + bt.x;
  y[1] = (v.y - mean) * inv * g.y + bt.y;
  y[2] = (v.z - mean) * inv * g.z + bt.z;
  y[3] = (v.w - mean) * inv * g.w + bt.w;
  size_t o = (size_t)row * 1024 + tid * 4;
#pragma unroll
  for (int j = 0; j < 4; ++j) {
    unsigned short hb = f2bf(y[j]);
    hi[o + j] = hb;
    if (SPLIT) lo[o + j] = f2bf(y[j] - bf2f(hb));
  }
}

// ---------------- GEMM: C[M,N] = A[M,K] * W[N,K]^T ----------------

template <bool SPLIT, bool BIAS, bool RESID, bool RELU, bool OUTBF16,
          int OUTMODE>
__global__ __launch_bounds__(256) void gemm_kernel(
    const short* __restrict__ Ah, const short* __restrict__ Al,
    const short* __restrict__ Bh, const short* __restrict__ Bl,
    const float* __restrict__ bias, const float* __restrict__ resid,
    void* __restrict__ outp, int M, int N, int K,
    unsigned short* __restrict__ qh, unsigned short* __restrict__ ql,
    unsigned short* __restrict__ kh, unsigned short* __restrict__ kl,
    unsigned short* __restrict__ vtp) {
  __shared__ short As[2][128 * 32];
  __shared__ short Bs[2][128 * 32];
  __shared__ short As2[SPLIT ? 2 : 1][SPLIT ? 128 * 32 : 8];
  __shared__ short Bs2[SPLIT ? 2 : 1][SPLIT ? 128 * 32 : 8];

  const int tid = threadIdx.x;
  const int lane = tid & 63;
  const int wid = tid >> 6;
  const int wr = (wid >> 1) << 6;
  const int wc = (wid & 1) << 6;
  const int l15 = lane & 15, lh = lane >> 4;
  const int rowBase = blockIdx.y << 7;
  const int colBase = blockIdx.x << 7;

  const int sr = tid >> 2;
  const int sc = (tid & 3) << 3;
  const int soff = sr * 32 + sc;
  const short* Ag = Ah + (size_t)(rowBase + sr) * K + sc;
  const short* Bg = Bh + (size_t)(colBase + sr) * K + sc;
  const short* Ag2 = SPLIT ? Al + (size_t)(rowBase + sr) * K + sc : nullptr;
  const short* Bg2 = SPLIT ? Bl + (size_t)(colBase + sr) * K + sc : nullptr;

  f32x4 acc[4][4];
#pragma unroll
  for (int m = 0; m < 4; ++m)
#pragma unroll
    for (int n = 0; n < 4; ++n) acc[m][n] = (f32x4){0.f, 0.f, 0.f, 0.f};

  const int kT = K >> 5;
  {
    gld16(Ag, &As[0][soff]);
    gld16(Ag + (size_t)64 * K, &As[0][soff + 64 * 32]);
    gld16(Bg, &Bs[0][soff]);
    gld16(Bg + (size_t)64 * K, &Bs[0][soff + 64 * 32]);
    if constexpr (SPLIT) {
      gld16(Ag2, &As2[0][soff]);
      gld16(Ag2 + (size_t)64 * K, &As2[0][soff + 64 * 32]);
      gld16(Bg2, &Bs2[0][soff]);
      gld16(Bg2 + (size_t)64 * K, &Bs2[0][soff + 64 * 32]);
    }
  }

  for (int kt = 0; kt < kT; ++kt) {
    __syncthreads();
    const int cb = kt & 1;
    if (kt + 1 < kT) {
      const int nb = cb ^ 1;
      const int k0 = (kt + 1) << 5;
      gld16(Ag + k0, &As[nb][soff]);
      gld16(Ag + k0 + (size_t)64 * K, &As[nb][soff + 64 * 32]);
      gld16(Bg + k0, &Bs[nb][soff]);
      gld16(Bg + k0 + (size_t)64 * K, &Bs[nb][soff + 64 * 32]);
      if constexpr (SPLIT) {
        gld16(Ag2 + k0, &As2[nb][soff]);
        gld16(Ag2 + k0 + (size_t)64 * K, &As2[nb][soff + 64 * 32]);
        gld16(Bg2 + k0, &Bs2[nb][soff]);
        gld16(Bg2 + k0 + (size_t)64 * K, &Bs2[nb][soff + 64 * 32]);
      }
    }

    const short* Asb = As[cb];
    const short* Bsb = Bs[cb];
    bf16x8 af[4], bfr[4];
#pragma unroll
    for (int m = 0; m < 4; ++m)
      af[m] = *(const bf16x8*)&Asb[(wr + m * 16 + l15) * 32 + lh * 8];
#pragma unroll
    for (int n = 0; n < 4; ++n)
      bfr[n] = *(const bf16x8*)&Bsb[(wc + n * 16 + l15) * 32 + lh * 8];
    if constexpr (SPLIT) {
      const short* Asb2 = As2[cb];
      const short* Bsb2 = Bs2[cb];
      bf16x8 af2[4], bfr2[4];
#pragma unroll
      for (int m = 0; m < 4; ++m)
        af2[m] = *(const bf16x8*)&Asb2[(wr + m * 16 + l15) * 32 + lh * 8];
#pragma unroll
      for (int n = 0; n < 4; ++n)
        bfr2[n] = *(const bf16x8*)&Bsb2[(wc + n * 16 + l15) * 32 + lh * 8];
#pragma unroll
      for (int m = 0; m < 4; ++m)
#pragma unroll
        for (int n = 0; n < 4; ++n) {
          acc[m][n] = __builtin_amdgcn_mfma_f32_16x16x32_bf16(af[m], bfr[n], acc[m][n], 0, 0, 0);
          acc[m][n] = __builtin_amdgcn_mfma_f32_16x16x32_bf16(af[m], bfr2[n], acc[m][n], 0, 0, 0);
          acc[m][n] = __builtin_amdgcn_mfma_f32_16x16x32_bf16(af2[m], bfr[n], acc[m][n], 0, 0, 0);
        }
    } else {
#pragma unroll
      for (int m = 0; m < 4; ++m)
#pragma unroll
        for (int n = 0; n < 4; ++n)
          acc[m][n] = __builtin_amdgcn_mfma_f32_16x16x32_bf16(af[m], bfr[n], acc[m][n], 0, 0, 0);
    }
  }

  const int prow = rowBase + wr + lh * 4;
  const int pcol = colBase + wc + l15;
#pragma unroll
  for (int m = 0; m < 4; ++m) {
#pragma unroll
    for (int n = 0; n < 4; ++n) {
      const int c = pcol + n * 16;
      float badd = 0.f;
      if constexpr (BIAS) badd = bias[c];
#pragma unroll
      for (int i = 0; i < 4; ++i) {
        const int r = prow + m * 16 + i;
        float v = acc[m][n][i] + badd;
        if constexpr (OUTMODE == 1) {
          const int part = c >> 10;
          const int cc = c & 1023;
          const int head = cc >> 6, dim = cc & 63;
          const int b = r >> 10, s = r & 1023;
          size_t idx = (((size_t)(b * 16 + head)) * 1024 + s) * 64 + dim;
          if (part == 0) {
            // fold 1/sqrt(dh) * log2(e) into Q -> softmax in exp2 domain
            float y = v * 0.18033688f;
            unsigned short hb = f2bf(y);
            qh[idx] = hb;
            ql[idx] = f2bf(y - bf2f(hb));
          } else {
            unsigned short hb = f2bf(v);
            kh[idx] = hb;
            kl[idx] = f2bf(v - bf2f(hb));
          }
        } else if constexpr (OUTMODE == 2) {
          const int head = c >> 6, dim = c & 63;
          const int b = r >> 10, s = r & 1023;
          vtp[(((size_t)(b * 16 + head)) * 64 + dim) * 1024 + s] = f2bf(v);
        } else {
          if constexpr (RESID) v += resid[(size_t)r * N + c];
          if constexpr (RELU) v = fmaxf(v, 0.f);
          if constexpr (OUTBF16)
            ((unsigned short*)outp)[(size_t)r * N + c] = f2bf(v);
          else
            ((float*)outp)[(size_t)r * N + c] = v;
        }
      }
    }
  }
}

// ---------------- attention: 32x32x16 MFMA flash, exp2 softmax ----------
// 512 blocks x 256 threads (4 waves x 32 q). XCD decode: blk&7 = xcd slot.
// Scores arrive in log2 units (Q pre-scaled by 0.125*log2e).

__global__ __launch_bounds__(256, 3) void attn_mfma_kernel(
    const short* __restrict__ qhi, const short* __restrict__ qlo,
    const short* __restrict__ khi, const short* __restrict__ klo,
    const short* __restrict__ vt, unsigned short* __restrict__ o,
    int S, int H) {
  __shared__ short Kh[2][64 * 64];
  __shared__ short Kl[2][64 * 64];
  __shared__ short Vs[2][64 * 64];

  const int tid = threadIdx.x, lane = tid & 63, wid = tid >> 6;
  const int l31 = lane & 31;
  const int hi = lane >> 5;
  const int blk = blockIdx.x;
  const int j = blk >> 3;
  const int bh = ((blk & 7) << 3) + (j & 7);
  const int q0 = (j >> 3) << 7;
  const size_t hbase = (size_t)bh * S * 64;

  const size_t qrow = hbase + (size_t)(q0 + wid * 32 + l31) * 64;
  bf16x8 qfh[4], qfl[4];
#pragma unroll
  for (int t = 0; t < 4; ++t) {
    qfh[t] = *(const bf16x8*)(qhi + qrow + t * 16 + hi * 8);
    qfl[t] = *(const bf16x8*)(qlo + qrow + t * 16 + hi * 8);
  }

  float m_run = -INFINITY, l_run = 0.f;
  f32x16 accO0, accO1;
#pragma unroll
  for (int r = 0; r < 16; ++r) { accO0[r] = 0.f; accO1[r] = 0.f; }

  const int r0 = tid >> 3, c0 = tid & 7;
  const int sw0 = ((c0 ^ (r0 & 7)) << 3);
  const int r1 = r0 + 32;
  const int sw1 = ((c0 ^ (r1 & 7)) << 3);

  const int nT = S >> 6;
  {
    gld16(khi + hbase + r0 * 64 + sw0, (char*)Kh[0] + tid * 16);
    gld16(khi + hbase + r1 * 64 + sw1, (char*)Kh[0] + tid * 16 + 4096);
    gld16(klo + hbase + r0 * 64 + sw0, (char*)Kl[0] + tid * 16);
    gld16(klo + hbase + r1 * 64 + sw1, (char*)Kl[0] + tid * 16 + 4096);
    gld16(vt + hbase + (size_t)r0 * S + sw0, (char*)Vs[0] + tid * 16);
    gld16(vt + hbase + (size_t)r1 * S + sw1, (char*)Vs[0] + tid * 16 + 4096);
  }

  for (int kt = 0; kt < nT; ++kt) {
    __syncthreads();
    const int cb = kt & 1;
    if (kt + 1 < nT) {
      const int nb = cb ^ 1;
      const size_t kb = hbase + (size_t)(kt + 1) * 64 * 64;
      gld16(khi + kb + r0 * 64 + sw0, (char*)Kh[nb] + tid * 16);
      gld16(khi + kb + r1 * 64 + sw1, (char*)Kh[nb] + tid * 16 + 4096);
      gld16(klo + kb + r0 * 64 + sw0, (char*)Kl[nb] + tid * 16);
      gld16(klo + kb + r1 * 64 + sw1, (char*)Kl[nb] + tid * 16 + 4096);
      const short* vg = vt + hbase + (size_t)(kt + 1) * 64;
      gld16(vg + (size_t)r0 * S + sw0, (char*)Vs[nb] + tid * 16);
      gld16(vg + (size_t)r1 * S + sw1, (char*)Vs[nb] + tid * 16 + 4096);
    }

    const short* KhB = Kh[cb];
    const short* KlB = Kl[cb];
    const short* VsB = Vs[cb];

    f32x16 sA, sB;
#pragma unroll
    for (int r = 0; r < 16; ++r) { sA[r] = 0.f; sB[r] = 0.f; }
    __builtin_amdgcn_s_setprio(1);
#pragma unroll
    for (int t = 0; t < 4; ++t) {
      const int cA = ((2 * t + hi) ^ (l31 & 7)) << 3;
      bf16x8 kh0 = *(const bf16x8*)&KhB[l31 * 64 + cA];
      bf16x8 kl0 = *(const bf16x8*)&KlB[l31 * 64 + cA];
      bf16x8 kh1 = *(const bf16x8*)&KhB[(32 + l31) * 64 + cA];
      bf16x8 kl1 = *(const bf16x8*)&KlB[(32 + l31) * 64 + cA];
      sA = __builtin_amdgcn_mfma_f32_32x32x16_bf16(kh0, qfh[t], sA, 0, 0, 0);
      sB = __builtin_amdgcn_mfma_f32_32x32x16_bf16(kh1, qfh[t], sB, 0, 0, 0);
      sA = __builtin_amdgcn_mfma_f32_32x32x16_bf16(kh0, qfl[t], sA, 0, 0, 0);
      sB = __builtin_amdgcn_mfma_f32_32x32x16_bf16(kh1, qfl[t], sB, 0, 0, 0);
      sA = __builtin_amdgcn_mfma_f32_32x32x16_bf16(kl0, qfh[t], sA, 0, 0, 0);
      sB = __builtin_amdgcn_mfma_f32_32x32x16_bf16(kl1, qfh[t], sB, 0, 0, 0);
    }
    __builtin_amdgcn_s_setprio(0);

    // balanced tile-max tree (depth ~5), then one half-swap combine
    float t8[8];
#pragma unroll
    for (int r = 0; r < 8; ++r)
      t8[r] = fmaxf(fmaxf(sA[2 * r], sA[2 * r + 1]),
                    fmaxf(sB[2 * r], sB[2 * r + 1]));
    float t4a = fmaxf(t8[0], t8[1]), t4b = fmaxf(t8[2], t8[3]);
    float t4c = fmaxf(t8[4], t8[5]), t4d = fmaxf(t8[6], t8[7]);
    float mt = fmaxf(fmaxf(t4a, t4b), fmaxf(t4c, t4d));
    {
      unsigned ma = __float_as_uint(mt), mb = ma;
      plswap(ma, mb);
      mt = fmaxf(__uint_as_float(ma), __uint_as_float(mb));
    }

    // defer-max: THR = 8 nats = 11.5 log2-units
    if (__any(mt > m_run + 11.5f)) {
      float mn = fmaxf(m_run, mt);
      float a = fexp2(m_run - mn);
      m_run = mn;
      l_run *= a;
#pragma unroll
      for (int r = 0; r < 16; ++r) {
        const int qq = (r & 3) + 8 * (r >> 2) + 4 * hi;
        float ar = __shfl(a, qq);
        accO0[r] *= ar;
        accO1[r] *= ar;
      }
    }

    // p = exp2(s - m) in place; partial l
    float ls = 0.f;
#pragma unroll
    for (int r = 0; r < 16; ++r) {
      sA[r] = fexp2(sA[r] - m_run);
      sB[r] = fexp2(sB[r] - m_run);
      ls += sA[r] + sB[r];
    }
    l_run += ls;

    // trunc-pack + half-swap into PV A-frags (v_perm + permlane only)
    unsigned a0 = pack2t(sA[0], sA[1]), a1 = pack2t(sA[2], sA[3]);
    unsigned a2 = pack2t(sA[4], sA[5]), a3 = pack2t(sA[6], sA[7]);
    plswap(a0, a2);
    plswap(a1, a3);
    unsigned b0 = pack2t(sA[8], sA[9]), b1 = pack2t(sA[10], sA[11]);
    unsigned b2 = pack2t(sA[12], sA[13]), b3 = pack2t(sA[14], sA[15]);
    plswap(b0, b2);
    plswap(b1, b3);
    unsigned c0_ = pack2t(sB[0], sB[1]), c1_ = pack2t(sB[2], sB[3]);
    unsigned c2_ = pack2t(sB[4], sB[5]), c3_ = pack2t(sB[6], sB[7]);
    plswap(c0_, c2_);
    plswap(c1_, c3_);
    unsigned d0 = pack2t(sB[8], sB[9]), d1 = pack2t(sB[10], sB[11]);
    unsigned d2 = pack2t(sB[12], sB[13]), d3 = pack2t(sB[14], sB[15]);
    plswap(d0, d2);
    plswap(d1, d3);

    bf16x8 pf0, pf1, pf2, pf3;
    {
      unsigned w[4];
      w[0] = a0; w[1] = a1; w[2] = a2; w[3] = a3;
      pf0 = *(bf16x8*)w;
      w[0] = b0; w[1] = b1; w[2] = b2; w[3] = b3;
      pf1 = *(bf16x8*)w;
      w[0] = c0_; w[1] = c1_; w[2] = c2_; w[3] = c3_;
      pf2 = *(bf16x8*)w;
      w[0] = d0; w[1] = d1; w[2] = d2; w[3] = d3;
      pf3 = *(bf16x8*)w;
    }

    __builtin_amdgcn_s_setprio(1);
    {
      const int d1r = 32 + l31;
#pragma unroll
      for (int c = 0; c < 4; ++c) {
        bf16x8 bv0 = *(const bf16x8*)&VsB[l31 * 64 + ((((2 * c + hi)) ^ (l31 & 7)) << 3)];
        bf16x8 bv1 = *(const bf16x8*)&VsB[d1r * 64 + ((((2 * c + hi)) ^ (d1r & 7)) << 3)];
        bf16x8 pf = (c == 0) ? pf0 : (c == 1) ? pf1 : (c == 2) ? pf2 : pf3;
        accO0 = __builtin_amdgcn_mfma_f32_32x32x16_bf16(pf, bv0, accO0, 0, 0, 0);
        accO1 = __builtin_amdgcn_mfma_f32_32x32x16_bf16(pf, bv1, accO1, 0, 0, 0);
      }
    }
    __builtin_amdgcn_s_setprio(0);
  }

  {
    unsigned la = __float_as_uint(l_run), lb = la;
    plswap(la, lb);
    l_run = __uint_as_float(la) + __uint_as_float(lb);
  }
  float lrec = 1.0f / l_run;

  const int b = bh >> 4, h = bh & 15;
#pragma unroll
  for (int r = 0; r < 16; ++r) {
    const int qq = (r & 3) + 8 * (r >> 2) + 4 * hi;
    float rr = __shfl(lrec, qq);
    const size_t row = (size_t)(b * S + q0 + wid * 32 + qq) * 1024 + h * 64;
    o[row + l31] = f2bf(accO0[r] * rr);
    o[row + 32 + l31] = f2bf(accO1[r] * rr);
  }
}

// ---------------- launch ----------------

extern "C" void kernel_launch(void* const* d_in, const int* in_sizes, int n_in,
                              void* d_out, int out_size, void* d_ws,
                              size_t ws_size, hipStream_t stream) {
  const float* x = (const float*)d_in[0];
  const float* in_project = (const float*)d_in[1];
  const float* out_project = (const float*)d_in[2];
  const float* ln1_g = (const float*)d_in[3];
  const float* ln1_b = (const float*)d_in[4];
  const float* w_up = (const float*)d_in[5];
  const float* b_up = (const float*)d_in[6];
  const float* w_down = (const float*)d_in[7];
  const float* b_down = (const float*)d_in[8];
  const float* ln2_g = (const float*)d_in[9];
  const float* ln2_b = (const float*)d_in[10];

  const int B = in_sizes[0] / (1024 * 1024);
  const int S = 1024, H = 16;
  const int M = B * S;  // 4096

  char* ws = (char*)d_ws;
  short* h_hi = (short*)(ws + 0);                 // 8MB
  short* h_lo = (short*)(ws + 8388608);           // 8MB
  float* x2 = (float*)(ws + 0);                   // 16MB, reuses h (dead)
  short* qhi = (short*)(ws + 16777216);           // 8MB
  short* qlo = (short*)(ws + 25165824);           // 8MB
  short* khi = (short*)(ws + 33554432);           // 8MB
  short* klo = (short*)(ws + 41943040);           // 8MB
  short* vt  = (short*)(ws + 50331648);           // 8MB
  short* o = (short*)(ws + 67108864);             // 8MB
  short* h2 = (short*)(ws + 75497472);            // 8MB
  short* u = (short*)(ws + 83886080);             // 16MB
  short* Wq_hi = (short*)(ws + 100663296);        // 6MB
  short* Wq_lo = (short*)(ws + 106954752);        // 6MB
  short* WoT = (short*)(ws + 113246208);          // 2MB
  short* WupT = (short*)(ws + 115343360);         // 4MB
  short* WdnT = (short*)(ws + 119537664);         // 4MB

  cast_split_kernel<<<2048, 256, 0, stream>>>(in_project, (unsigned short*)Wq_hi,
                                              (unsigned short*)Wq_lo, 3072 * 1024);
  transpose3_kernel<<<dim3(64, 64, 3), dim3(32, 8), 0, stream>>>(
      out_project, w_up, w_down, (unsigned short*)WoT, (unsigned short*)WupT,
      (unsigned short*)WdnT);

  ln_kernel<true><<<M, 256, 0, stream>>>(x, ln1_g, ln1_b, (unsigned short*)h_hi,
                                         (unsigned short*)h_lo);

  gemm_kernel<true, false, false, false, false, 1>
      <<<dim3(2048 / 128, M / 128), 256, 0, stream>>>(
          h_hi, h_lo, Wq_hi, Wq_lo, nullptr, nullptr, nullptr, M, 2048, 1024,
          (unsigned short*)qhi, (unsigned short*)qlo, (unsigned short*)khi,
          (unsigned short*)klo, nullptr);

  gemm_kernel<false, false, false, false, false, 2>
      <<<dim3(1024 / 128, M / 128), 256, 0, stream>>>(
          h_hi, nullptr, Wq_hi + (size_t)2048 * 1024, nullptr, nullptr, nullptr,
          nullptr, M, 1024, 1024, nullptr, nullptr, nullptr, nullptr,
          (unsigned short*)vt);

  attn_mfma_kernel<<<512, 256, 0, stream>>>(
      qhi, qlo, khi, klo, vt, (unsigned short*)o, S, H);

  gemm_kernel<false, false, true, false, false, 0>
      <<<dim3(1024 / 128, M / 128), 256, 0, stream>>>(
          o, nullptr, WoT, nullptr, nullptr, x, x2, M, 1024, 1024,
          nullptr, nullptr, nullptr, nullptr, nullptr);

  ln_kernel<false><<<M, 256, 0, stream>>>(x2, ln2_g, ln2_b,
                                          (unsigned short*)h2, nullptr);

  gemm_kernel<false, true, false, true, true, 0>
      <<<dim3(2048 / 128, M / 128), 256, 0, stream>>>(
          h2, nullptr, WupT, nullptr, b_up, nullptr, u, M, 2048, 1024,
          nullptr, nullptr, nullptr, nullptr, nullptr);

  gemm_kernel<false, true, true, false, false, 0>
      <<<dim3(1024 / 128, M / 128), 256, 0, stream>>>(
          u, nullptr, WdnT, nullptr, b_down, x2, d_out, M, 1024, 2048,
          nullptr, nullptr, nullptr, nullptr, nullptr);
}